// Round 5
// baseline (229.039 us; speedup 1.0000x reference)
//
#include <hip/hip_runtime.h>

typedef unsigned short ushort;
typedef __attribute__((ext_vector_type(8))) short bf16x8;
typedef __attribute__((ext_vector_type(4))) float f32x4;
typedef __attribute__((ext_vector_type(4))) ushort us4;

#define NBATCH 32
#define ICN 256
#define OCN 256
#define HSZ 56
#define WSZ 56
#define HP 58
#define SPAT (HP*HP)            /* 3364 */
#define KTOT 2304               /* 9*256, k = (kh*3+kw)*256 + ic */
#define MTOT (NBATCH*HSZ*WSZ)   /* 100352 */
#define NT   (KTOT/64)          /* 36 K-tiles of BK=64 */

#define XP_BYTES ((size_t)NBATCH*SPAT*ICN*2)   /* 55,115,776 */
#define WD_BYTES ((size_t)OCN*KTOT*4)          /* 2,359,296  */

__device__ __forceinline__ ushort f2bf(float f) {
  union { float f; unsigned u; } c; c.f = f;
  unsigned r = c.u + 0x7FFFu + ((c.u >> 16) & 1u);
  return (ushort)(r >> 16);
}

// x [N][IC][56][56] f32 -> xp [N][58][58][IC] bf16, halo rows/cols written as 0
__global__ void k_transpose(const float* __restrict__ x, ushort* __restrict__ xp) {
  __shared__ float tile[ICN*57];   // stride 57: conflict-free transpose read
  int h = blockIdx.x, n = blockIdx.y;          // h = padded row 0..57
  ushort* dst = xp + ((size_t)n*SPAT + (size_t)h*HP)*ICN;
  if (h == 0 || h == HP-1) {
    for (int e = threadIdx.x; e < HP*ICN/4; e += 256) ((us4*)dst)[e] = (us4){0,0,0,0};
    return;
  }
  const float* src = x + ((size_t)n*ICN*HSZ*WSZ) + (size_t)(h-1)*WSZ;
  for (int e = threadIdx.x; e < ICN*WSZ; e += 256) {
    int ic = e / WSZ, w = e - ic*WSZ;                 // w fastest -> coalesced read
    tile[ic*57 + w] = src[(size_t)ic*(HSZ*WSZ) + w];
  }
  __syncthreads();
  for (int e = threadIdx.x; e < ICN*HP; e += 256) {   // e = w*256+ic, w=0..57
    int w = e >> 8, ic = e & 255;
    dst[e] = (w == 0 || w == HP-1) ? (ushort)0 : f2bf(tile[ic*57 + (w-1)]);
  }
}

// COO scatter into dense fp32 W [oc][k], duplicates sum via atomicAdd
__global__ void k_scatter(const int* __restrict__ idx, const float* __restrict__ val,
                          float* __restrict__ wd, int nnz) {
  int i = blockIdx.x*256 + threadIdx.x;
  if (i >= nnz) return;
  int id = idx[i];
  int oc = id / (ICN*9);
  int rem = id - oc*(ICN*9);
  int ic = rem / 9;
  int k9 = rem - ic*9;                                // kh*3+kw
  atomicAdd(wd + (size_t)oc*KTOT + k9*ICN + ic, val[i]);
}

__global__ void k_convert(const float* __restrict__ wd, ushort* __restrict__ bm) {
  int i = (blockIdx.x*256 + threadIdx.x)*4;
  float4 v = *(const float4*)(wd + i);
  us4 o; o[0]=f2bf(v.x); o[1]=f2bf(v.y); o[2]=f2bf(v.z); o[3]=f2bf(v.w);
  *(us4*)(bm + i) = o;
}

// ------------- 128x128 implicit-GEMM, 4-phase counted-vmcnt, 2 blocks/CU -----
// out[m][oc] = sum_k A[m][k]*B[oc][k].  BM=BN=128, BK=64, 256 thr = 4 waves
// (2M x 2N, 64x64 C each).  LDS 64KB -> 2 blocks/CU: co-resident blocks
// dephase, overlapping one block's LDS/barrier windows with the other's MFMAs
// (m114 mechanism).  Same verified schedule as the 256^2 version: 4 stage
// units/tile {A-kh0,B-kh0,A-kh1,B-kh1} (2 gld_lds/thread each), vmcnt(4)
// twice per tile (never 0 in main loop), inline-asm ds_read + lgkmcnt(0) +
// sched_barrier(0) (rule #18), 2-bit XOR swizzle on both sides (rule #21).

#define GLD(gsrc, ldst) __builtin_amdgcn_global_load_lds( \
    (const __attribute__((address_space(1))) void*)(gsrc), \
    (__attribute__((address_space(3))) void*)(ldst), 16, 0, 0)
#define BAR()  asm volatile("s_barrier" ::: "memory")
#define VMW4() asm volatile("s_waitcnt vmcnt(4)" ::: "memory")
#define VMW0() asm volatile("s_waitcnt vmcnt(0)" ::: "memory")
#define LGKM0SB() do { asm volatile("s_waitcnt lgkmcnt(0)" ::: "memory"); \
                       __builtin_amdgcn_sched_barrier(0); } while (0)

#define STAGE_A(T1, KH) do { \
    const int t4_ = (T1) >> 2; const int khh_ = t4_/3, khw_ = t4_ - khh_*3; \
    const int off_ = ((khh_*HP + khw_) << 8) + (((T1) & 3) << 6) + ((KH) << 5); \
    ushort* b_ = &Ab[(((T1)&1)*2 + (KH))*4096]; \
    GLD(xp + srcA0 + off_, b_ + ldsSlot0); \
    GLD(xp + srcA1 + off_, b_ + ldsSlot1); } while (0)

#define STAGE_B(T1, KH) do { \
    const int off_ = (T1)*64 + ((KH) << 5); \
    ushort* b_ = &Bb[(((T1)&1)*2 + (KH))*4096]; \
    GLD(bm + srcB0 + off_, b_ + ldsSlot0); \
    GLD(bm + srcB1 + off_, b_ + ldsSlot1); } while (0)

// A fragments: 4 x ds_read_b128 (all 4 m-frags of this wave's 64 rows, one kh)
#define LOADA(KH, C) do { \
    unsigned a_ = AbB + (unsigned)(((C)*2+(KH))*8192) + aLane; \
    asm volatile("ds_read_b128 %0, %4 offset:0\n\t" \
                 "ds_read_b128 %1, %4 offset:1024\n\t" \
                 "ds_read_b128 %2, %4 offset:2048\n\t" \
                 "ds_read_b128 %3, %4 offset:3072" \
                 : "=&v"(av[0]), "=&v"(av[1]), "=&v"(av[2]), "=&v"(av[3]) \
                 : "v"(a_)); } while (0)

// B fragments: 2 x ds_read_b128 (one n-half = 32 cols of this wave's 64)
#define LOADB2(KH, NH, C) do { \
    unsigned a_ = BbB + (unsigned)(((C)*2+(KH))*8192 + (NH)*2048) + bLane; \
    asm volatile("ds_read_b128 %0, %2 offset:0\n\t" \
                 "ds_read_b128 %1, %2 offset:1024" \
                 : "=&v"(bv[0]), "=&v"(bv[1]) \
                 : "v"(a_)); } while (0)

#define MFMA8(NH) do { \
    _Pragma("unroll") \
    for (int f_ = 0; f_ < 4; ++f_) { \
      _Pragma("unroll") \
      for (int n_ = 0; n_ < 2; ++n_) \
        acc[f_][(NH)*2+n_] = __builtin_amdgcn_mfma_f32_16x16x32_bf16( \
            av[f_], bv[n_], acc[f_][(NH)*2+n_], 0, 0, 0); \
    } } while (0)

__global__ __launch_bounds__(256, 2) void k_gemm4(const ushort* __restrict__ xp,
                                                  const ushort* __restrict__ bm,
                                                  const float* __restrict__ bias,
                                                  float* __restrict__ out) {
  // [2 buf][2 khalf][128 rows][32 k] bf16 each => 32KB + 32KB = 64KB LDS
  __shared__ __align__(16) ushort Ab[2*2*128*32];
  __shared__ __align__(16) ushort Bb[2*2*128*32];

  const int tid = threadIdx.x;
  const int lam = tid & 63;
  const int wv  = tid >> 6;            // 0..3
  const int wr  = wv >> 1;             // 0..1  (M half)
  const int wc  = wv & 1;              // 0..1  (N half)
  const int la  = lam & 15;
  const int pq  = (lam >> 4) ^ ((la >> 1) & 3);      // read-side physical quad
  const int m0  = blockIdx.x * 128;
  const int oc0 = blockIdx.y * 128;

  const unsigned AbB = (unsigned)(uintptr_t)(__attribute__((address_space(3))) char*)Ab;
  const unsigned BbB = (unsigned)(uintptr_t)(__attribute__((address_space(3))) char*)Bb;

  // fragment read lane offsets (bytes within one 8KB khalf region)
  const unsigned aLane = wr*4096 + la*64 + pq*16;
  const unsigned bLane = wc*4096 + la*64 + pq*16;

  // staging: slot row r = (i*4+wv)*16 + (lam>>2), physical quad lam&3,
  // logical octet q = (lam&3) ^ ((lam>>3)&3)  (inverse of read swizzle)
  const int qs = (lam & 3) ^ ((lam >> 3) & 3);
  int srcA0, srcA1, srcB0, srcB1;
  const int ldsSlot0 = (0*4 + wv)*512;   // wave-uniform ushort offsets
  const int ldsSlot1 = (1*4 + wv)*512;
  {
    int r0 = (0*4 + wv)*16 + (lam >> 2);
    int r1 = (1*4 + wv)*16 + (lam >> 2);
    int m, n, rem, oh, ow;
    m = m0 + r0; n = m/3136; rem = m - n*3136; oh = rem/56; ow = rem - oh*56;
    srcA0 = (n*SPAT + oh*HP + ow)*ICN + qs*8;
    m = m0 + r1; n = m/3136; rem = m - n*3136; oh = rem/56; ow = rem - oh*56;
    srcA1 = (n*SPAT + oh*HP + ow)*ICN + qs*8;
    srcB0 = (oc0 + r0)*KTOT + qs*8;
    srcB1 = (oc0 + r1)*KTOT + qs*8;
  }

  f32x4 acc[4][4];
#pragma unroll
  for (int a = 0; a < 4; ++a)
#pragma unroll
    for (int b = 0; b < 4; ++b) acc[a][b] = (f32x4){0.f, 0.f, 0.f, 0.f};

  bf16x8 av[4];
  bf16x8 bv[2];

  // prologue: stage tile 0, keep its kh1 units in flight
  STAGE_A(0, 0); STAGE_B(0, 0); STAGE_A(0, 1); STAGE_B(0, 1);
  VMW4();
  BAR();

  for (int t = 0; t < NT-1; ++t) {
    const int c = t & 1;
    // phase 0: kh0, nh0  | stage A-kh0(t+1)
    LOADA(0, c); LOADB2(0, 0, c);
    STAGE_A(t+1, 0);
    BAR();
    LGKM0SB();
    __builtin_amdgcn_s_setprio(1); MFMA8(0); __builtin_amdgcn_s_setprio(0);
    BAR();
    // phase 1: kh0, nh1  | stage B-kh0(t+1) | vmcnt(4): kh1(t) landed
    LOADB2(0, 1, c);
    STAGE_B(t+1, 0);
    BAR();
    LGKM0SB();
    __builtin_amdgcn_s_setprio(1); MFMA8(1); __builtin_amdgcn_s_setprio(0);
    VMW4();
    BAR();
    // phase 2: kh1, nh0  | stage A-kh1(t+1)
    LOADA(1, c); LOADB2(1, 0, c);
    STAGE_A(t+1, 1);
    BAR();
    LGKM0SB();
    __builtin_amdgcn_s_setprio(1); MFMA8(0); __builtin_amdgcn_s_setprio(0);
    BAR();
    // phase 3: kh1, nh1  | stage B-kh1(t+1) | vmcnt(4): kh0(t+1) landed
    LOADB2(1, 1, c);
    STAGE_B(t+1, 1);
    BAR();
    LGKM0SB();
    __builtin_amdgcn_s_setprio(1); MFMA8(1); __builtin_amdgcn_s_setprio(0);
    VMW4();
    BAR();
  }

  // peeled last tile (t = NT-1): no staging; drain before kh1 reads
  {
    const int c = (NT-1) & 1;
    LOADA(0, c); LOADB2(0, 0, c);
    BAR();
    LGKM0SB();
    __builtin_amdgcn_s_setprio(1); MFMA8(0); __builtin_amdgcn_s_setprio(0);
    BAR();
    LOADB2(0, 1, c);
    BAR();
    LGKM0SB();
    __builtin_amdgcn_s_setprio(1); MFMA8(1); __builtin_amdgcn_s_setprio(0);
    VMW0();
    BAR();
    LOADA(1, c); LOADB2(1, 0, c);
    BAR();
    LGKM0SB();
    __builtin_amdgcn_s_setprio(1); MFMA8(0); __builtin_amdgcn_s_setprio(0);
    BAR();
    LOADB2(1, 1, c);
    LGKM0SB();
    __builtin_amdgcn_s_setprio(1); MFMA8(1); __builtin_amdgcn_s_setprio(0);
  }

  // epilogue: lane l -> col(oc) = la, rows m = base + (l>>4)*4 + j
#pragma unroll
  for (int nn = 0; nn < 4; ++nn) {
    int oc = oc0 + wc*64 + nn*16 + la;
    float bvs = bias[oc];
#pragma unroll
    for (int mf = 0; mf < 4; ++mf) {
      int m = m0 + wr*64 + mf*16 + ((lam >> 4) << 2);
      int n = m / 3136;
      int rem = m - n*3136;     // float4 never straddles n (3136 % 4 == 0)
      float4 o;
      o.x = acc[mf][nn][0] + bvs;
      o.y = acc[mf][nn][1] + bvs;
      o.z = acc[mf][nn][2] + bvs;
      o.w = acc[mf][nn][3] + bvs;
      *(float4*)(out + ((size_t)(n*OCN + oc))*3136 + rem) = o;
    }
  }
}

extern "C" void kernel_launch(void* const* d_in, const int* in_sizes, int n_in,
                              void* d_out, int out_size, void* d_ws, size_t ws_size,
                              hipStream_t stream) {
  const float* x    = (const float*)d_in[0];
  const float* wval = (const float*)d_in[1];
  const int*   widx = (const int*)d_in[2];
  const float* bias = (const float*)d_in[3];
  float* out = (float*)d_out;
  const int nnz = in_sizes[1];

  char* ws = (char*)d_ws;
  ushort* xp = (ushort*)ws;                               // 55.1 MB
  float*  wd = (float*)(ws + XP_BYTES);                   // 2.36 MB
  ushort* bm = (ushort*)(ws + XP_BYTES + WD_BYTES);       // 1.18 MB

  hipMemsetAsync(wd, 0, WD_BYTES, stream);
  k_transpose<<<dim3(HP, NBATCH), 256, 0, stream>>>(x, xp);
  k_scatter<<<dim3((nnz + 255)/256), 256, 0, stream>>>(widx, wval, wd, nnz);
  k_convert<<<dim3((OCN*KTOT)/(256*4)), 256, 0, stream>>>(wd, bm);
  k_gemm4<<<dim3(MTOT/128, OCN/128), 256, 0, stream>>>(xp, bm, bias, out);
}

// Round 6
// 193.961 us; speedup vs baseline: 1.1809x; 1.1809x over previous
//
#include <hip/hip_runtime.h>

typedef unsigned short ushort;
typedef __attribute__((ext_vector_type(8))) short bf16x8;
typedef __attribute__((ext_vector_type(4))) float f32x4;
typedef __attribute__((ext_vector_type(4))) ushort us4;

#define NBATCH 32
#define ICN 256
#define OCN 256
#define HSZ 56
#define WSZ 56
#define HP 58
#define SPAT (HP*HP)            /* 3364 */
#define KTOT 2304               /* 9*256, k = (kh*3+kw)*256 + ic */
#define MTOT (NBATCH*HSZ*WSZ)   /* 100352 */
#define NT   (KTOT/64)          /* 36 K-tiles of BK=64 */

#define XP_BYTES ((size_t)NBATCH*SPAT*ICN*2)    /* 55,115,776 */
#define WD_BYTES ((size_t)OCN*KTOT*4)           /* 2,359,296  */
#define BM2_BYTES ((size_t)(NT+1)*2*1024*16)    /* 1.21 MB (+1 tile slack) */

__device__ __forceinline__ ushort f2bf(float f) {
  union { float f; unsigned u; } c; c.f = f;
  unsigned r = c.u + 0x7FFFu + ((c.u >> 16) & 1u);
  return (ushort)(r >> 16);
}

// x [N][IC][56][56] f32 -> xp [N][58][58][IC] bf16, halo rows/cols written as 0
__global__ void k_transpose(const float* __restrict__ x, ushort* __restrict__ xp) {
  __shared__ float tile[ICN*57];   // stride 57: conflict-free transpose read
  int h = blockIdx.x, n = blockIdx.y;          // h = padded row 0..57
  ushort* dst = xp + ((size_t)n*SPAT + (size_t)h*HP)*ICN;
  if (h == 0 || h == HP-1) {
    for (int e = threadIdx.x; e < HP*ICN/4; e += 256) ((us4*)dst)[e] = (us4){0,0,0,0};
    return;
  }
  const float* src = x + ((size_t)n*ICN*HSZ*WSZ) + (size_t)(h-1)*WSZ;
  for (int e = threadIdx.x; e < ICN*WSZ; e += 256) {
    int ic = e / WSZ, w = e - ic*WSZ;                 // w fastest -> coalesced read
    tile[ic*57 + w] = src[(size_t)ic*(HSZ*WSZ) + w];
  }
  __syncthreads();
  for (int e = threadIdx.x; e < ICN*HP; e += 256) {   // e = w*256+ic, w=0..57
    int w = e >> 8, ic = e & 255;
    dst[e] = (w == 0 || w == HP-1) ? (ushort)0 : f2bf(tile[ic*57 + (w-1)]);
  }
}

// COO scatter into dense fp32 W [oc][k], duplicates sum via atomicAdd
__global__ void k_scatter(const int* __restrict__ idx, const float* __restrict__ val,
                          float* __restrict__ wd, int nnz) {
  int i = blockIdx.x*256 + threadIdx.x;
  if (i >= nnz) return;
  int id = idx[i];
  int oc = id / (ICN*9);
  int rem = id - oc*(ICN*9);
  int ic = rem / 9;
  int k9 = rem - ic*9;                                // kh*3+kw
  atomicAdd(wd + (size_t)oc*KTOT + k9*ICN + ic, val[i]);
}

// Pre-tile B into LDS-slot order with quad swizzle baked in.
// Unit (t, kh) = [256 oc][4 phys quads]; slot s: r=s>>2, p=s&3,
// logical octet o = p ^ ((r>>1)&3).  bm2[e]*8 = 8 bf16 of wd[r][k(t,kh,o)..+8].
__global__ void k_convert2(const float* __restrict__ wd, ushort* __restrict__ bm2) {
  int e = blockIdx.x*256 + threadIdx.x;      // 0 .. NT*2*1024-1
  int t  = e >> 11;
  int kh = (e >> 10) & 1;
  int s  = e & 1023;
  int r  = s >> 2;
  int p  = s & 3;
  int o  = p ^ ((r >> 1) & 3);
  int t4 = t >> 2;
  int k  = t4*256 + ((t & 3) << 6) + (kh << 5) + o*8;
  const float* src = wd + (size_t)r*KTOT + k;
  float4 v0 = *(const float4*)(src);
  float4 v1 = *(const float4*)(src + 4);
  us4 lo, hi;
  lo[0]=f2bf(v0.x); lo[1]=f2bf(v0.y); lo[2]=f2bf(v0.z); lo[3]=f2bf(v0.w);
  hi[0]=f2bf(v1.x); hi[1]=f2bf(v1.y); hi[2]=f2bf(v1.z); hi[3]=f2bf(v1.w);
  ushort* dst = bm2 + (size_t)e*8;
  *(us4*)(dst) = lo; *(us4*)(dst+4) = hi;
}

// ---------------- 256x256 implicit-GEMM, contiguous staging ------------------
// A LDS: [2 buf][2 u=row-half][128 r][8 phys octets x 16B], swz p=o^(r&7)
//   -> per gld_lds: 8 rows x 128B contiguous source runs.
// B LDS: [2 buf][2 kh][256 r][4 phys quads x 16B], swz p=o^((r>>1)&3),
//   source bm2 pre-tiled in slot order -> per gld_lds: 1KB contiguous.
// Staging order per tile t: ph0 Au0(t+1), ph1 Au1(t+1), ph2 Bk0(t+2),
// ph3 Bk1(t+1).  Waits: VMW6 @ph1-end (guards Bk1(t) for ph2),
// VMW4 @ph3-end (guards Au*,Bk0 of t+1 for ph0).  Never 0 in main loop.

#define GLD(gsrc, ldst) __builtin_amdgcn_global_load_lds( \
    (const __attribute__((address_space(1))) void*)(gsrc), \
    (__attribute__((address_space(3))) void*)(ldst), 16, 0, 0)
#define BAR()  asm volatile("s_barrier" ::: "memory")
#define VMW6() asm volatile("s_waitcnt vmcnt(6)" ::: "memory")
#define VMW4() asm volatile("s_waitcnt vmcnt(4)" ::: "memory")
#define VMW0() asm volatile("s_waitcnt vmcnt(0)" ::: "memory")
#define LGKM0SB() do { asm volatile("s_waitcnt lgkmcnt(0)" ::: "memory"); \
                       __builtin_amdgcn_sched_barrier(0); } while (0)

#define STAGE_AU(T1, U) do { \
    const int t4_ = (T1) >> 2; const int khh_ = t4_/3, khw_ = t4_ - khh_*3; \
    const int koff_ = (khh_*HP + khw_)*256 + (((T1) & 3) << 6); \
    ushort* d_ = &Ab[(((T1)&1)*16384) + (U)*8192]; \
    GLD(xp + ((U) ? srcA10 : srcA00) + koff_, d_ + ldsOff0); \
    GLD(xp + ((U) ? srcA11 : srcA01) + koff_, d_ + ldsOff1); } while (0)

#define STAGE_BK(T1, KH) do { \
    const ushort* s_ = bm2 + ((size_t)((T1)*2 + (KH)))*8192; \
    ushort* d_ = &Bb[(((T1)&1)*16384) + (KH)*8192]; \
    GLD(s_ + srcB0, d_ + ldsOff0); \
    GLD(s_ + srcB1, d_ + ldsOff1); } while (0)

#define LOADA(KH, MH, C) do { \
    unsigned a_ = ((KH) ? aL1v : aL0v) + (unsigned)((C)*32768 + (MH)*8192); \
    asm volatile("ds_read_b128 %0, %4 offset:0\n\t" \
                 "ds_read_b128 %1, %4 offset:2048\n\t" \
                 "ds_read_b128 %2, %4 offset:4096\n\t" \
                 "ds_read_b128 %3, %4 offset:6144" \
                 : "=&v"(av[0]), "=&v"(av[1]), "=&v"(av[2]), "=&v"(av[3]) \
                 : "v"(a_)); } while (0)

#define LOADB(KH, C) do { \
    unsigned a_ = bLv + (unsigned)((C)*32768 + (KH)*16384); \
    asm volatile("ds_read_b128 %0, %4 offset:0\n\t" \
                 "ds_read_b128 %1, %4 offset:1024\n\t" \
                 "ds_read_b128 %2, %4 offset:2048\n\t" \
                 "ds_read_b128 %3, %4 offset:3072" \
                 : "=&v"(bv[0]), "=&v"(bv[1]), "=&v"(bv[2]), "=&v"(bv[3]) \
                 : "v"(a_)); } while (0)

#define MFMA16(MH) do { \
    _Pragma("unroll") \
    for (int f_ = 0; f_ < 4; ++f_) { \
      _Pragma("unroll") \
      for (int n_ = 0; n_ < 4; ++n_) \
        acc[(MH)*4+f_][n_] = __builtin_amdgcn_mfma_f32_16x16x32_bf16( \
            av[f_], bv[n_], acc[(MH)*4+f_][n_], 0, 0, 0); \
    } } while (0)

__global__ __launch_bounds__(512, 2) void k_gemm8(const ushort* __restrict__ xp,
                                                  const ushort* __restrict__ bm2,
                                                  const float* __restrict__ bias,
                                                  float* __restrict__ out) {
  __shared__ __align__(128) ushort Ab[2*2*128*64];   // 64 KB
  __shared__ __align__(128) ushort Bb[2*2*256*32];   // 64 KB

  const int tid = threadIdx.x;
  const int lam = tid & 63;
  const int wv  = tid >> 6;            // 0..7
  const int wr  = wv >> 2;             // 0..1  (M half -> A unit)
  const int wc  = wv & 3;              // 0..3  (N quarter)
  const int la  = lam & 15;
  const int m0  = blockIdx.x * 256;

  const unsigned AbB = (unsigned)(uintptr_t)(__attribute__((address_space(3))) char*)Ab;
  const unsigned BbB = (unsigned)(uintptr_t)(__attribute__((address_space(3))) char*)Bb;

  // A read bases: byte addr = AbB + buf*32768 + u*16384 + r*128 + p*16,
  // r = mh*64+f*16+la, p = (kh*4 + oq) ^ (la&7), oq = lam>>4.
  const int q0 = (lam >> 4) ^ (la & 7);
  const unsigned aL0v = AbB + wr*16384 + la*128 + q0*16;
  const unsigned aL1v = AbB + wr*16384 + la*128 + (q0 ^ 4)*16;
  // B read base: byte addr = BbB + buf*32768 + kh*16384 + r*64 + p*16,
  // r = wc*64+f*16+la, p = (lam>>4) ^ ((la>>1)&3).
  const int pq = (lam >> 4) ^ ((la >> 1) & 3);
  const unsigned bLv = BbB + wc*4096 + la*64 + pq*16;

  // staging lane geometry (both A and B: per wave 2 instrs of 64 slots)
  const int ldsOff0 = (0*8 + wv)*512;          // ushort offsets, wave-uniform
  const int ldsOff1 = (1*8 + wv)*512;
  const int srcB0 = (0*8 + wv)*512 + lam*8;    // bm2 pre-tiled: contiguous
  const int srcB1 = (1*8 + wv)*512 + lam*8;
  // A: unit u, instr i: row r = (i*8+wv)*8 + (lam>>3); phys octet p = lam&7;
  // logical octet o = p ^ (r&7) = (lam&7) ^ (lam>>3).
  int srcA00, srcA01, srcA10, srcA11;
  {
    const int oA = (lam & 7) ^ (lam >> 3);
    int m, n, rem, oh, ow, r;
    r = (0*8 + wv)*8 + (lam >> 3);
    m = m0 + 0*128 + r; n = m/3136; rem = m - n*3136; oh = rem/56; ow = rem - oh*56;
    srcA00 = (n*SPAT + oh*HP + ow)*ICN + oA*8;
    r = (1*8 + wv)*8 + (lam >> 3);
    m = m0 + 0*128 + r; n = m/3136; rem = m - n*3136; oh = rem/56; ow = rem - oh*56;
    srcA01 = (n*SPAT + oh*HP + ow)*ICN + oA*8;
    r = (0*8 + wv)*8 + (lam >> 3);
    m = m0 + 1*128 + r; n = m/3136; rem = m - n*3136; oh = rem/56; ow = rem - oh*56;
    srcA10 = (n*SPAT + oh*HP + ow)*ICN + oA*8;
    r = (1*8 + wv)*8 + (lam >> 3);
    m = m0 + 1*128 + r; n = m/3136; rem = m - n*3136; oh = rem/56; ow = rem - oh*56;
    srcA11 = (n*SPAT + oh*HP + ow)*ICN + oA*8;
  }

  f32x4 acc[8][4];
#pragma unroll
  for (int a = 0; a < 8; ++a)
#pragma unroll
    for (int b = 0; b < 4; ++b) acc[a][b] = (f32x4){0.f, 0.f, 0.f, 0.f};

  bf16x8 av[4], bv[4];

  // prologue: fill pipeline to steady state (in-flight after wait = 4)
  STAGE_AU(0, 0); STAGE_AU(0, 1); STAGE_BK(0, 0); STAGE_BK(0, 1); STAGE_BK(1, 0);
  VMW4();
  BAR();

  for (int t = 0; t < NT-1; ++t) {
    const int c = t & 1;
    // phase 0: kh0, mh0  | stage A-u0(t+1)
    LOADB(0, c); LOADA(0, 0, c);
    STAGE_AU(t+1, 0);
    BAR();
    LGKM0SB();
    __builtin_amdgcn_s_setprio(1); MFMA16(0); __builtin_amdgcn_s_setprio(0);
    BAR();
    // phase 1: kh0, mh1  | stage A-u1(t+1) | VMW6: Bk1(t) landed (for ph2)
    LOADA(0, 1, c);
    STAGE_AU(t+1, 1);
    BAR();
    LGKM0SB();
    __builtin_amdgcn_s_setprio(1); MFMA16(1); __builtin_amdgcn_s_setprio(0);
    VMW6();
    BAR();
    // phase 2: kh1, mh0  | stage B-kh0(t+2)  (region's last read was ph0 -> safe)
    LOADB(1, c); LOADA(1, 0, c);
    STAGE_BK(t+2, 0);
    BAR();
    LGKM0SB();
    __builtin_amdgcn_s_setprio(1); MFMA16(0); __builtin_amdgcn_s_setprio(0);
    BAR();
    // phase 3: kh1, mh1  | stage B-kh1(t+1) | VMW4: Au0,Au1,Bk0 of t+1 landed
    LOADA(1, 1, c);
    STAGE_BK(t+1, 1);
    BAR();
    LGKM0SB();
    __builtin_amdgcn_s_setprio(1); MFMA16(1); __builtin_amdgcn_s_setprio(0);
    VMW4();
    BAR();
  }

  // peeled last tile (t = NT-1): no staging
  {
    const int c = (NT-1) & 1;
    LOADB(0, c); LOADA(0, 0, c);
    BAR();
    LGKM0SB();
    __builtin_amdgcn_s_setprio(1); MFMA16(0); __builtin_amdgcn_s_setprio(0);
    BAR();
    LOADA(0, 1, c);
    BAR();
    LGKM0SB();
    __builtin_amdgcn_s_setprio(1); MFMA16(1); __builtin_amdgcn_s_setprio(0);
    VMW0();                      // drain Bk1(NT-1) (+ junk Bk0(NT))
    BAR();
    LOADB(1, c); LOADA(1, 0, c);
    BAR();
    LGKM0SB();
    __builtin_amdgcn_s_setprio(1); MFMA16(0); __builtin_amdgcn_s_setprio(0);
    BAR();
    LOADA(1, 1, c);
    LGKM0SB();
    __builtin_amdgcn_s_setprio(1); MFMA16(1); __builtin_amdgcn_s_setprio(0);
  }

  // epilogue: lane l -> col(oc) = la, rows m = base + (l>>4)*4 + j
#pragma unroll
  for (int nn = 0; nn < 4; ++nn) {
    int oc = wc*64 + nn*16 + la;
    float bvs = bias[oc];
#pragma unroll
    for (int mf = 0; mf < 8; ++mf) {
      int m = m0 + wr*128 + mf*16 + ((lam >> 4) << 2);
      int n = m / 3136;
      int rem = m - n*3136;     // float4 never straddles n (3136 % 4 == 0)
      float4 o;
      o.x = acc[mf][nn][0] + bvs;
      o.y = acc[mf][nn][1] + bvs;
      o.z = acc[mf][nn][2] + bvs;
      o.w = acc[mf][nn][3] + bvs;
      *(float4*)(out + ((size_t)(n*OCN + oc))*3136 + rem) = o;
    }
  }
}

extern "C" void kernel_launch(void* const* d_in, const int* in_sizes, int n_in,
                              void* d_out, int out_size, void* d_ws, size_t ws_size,
                              hipStream_t stream) {
  const float* x    = (const float*)d_in[0];
  const float* wval = (const float*)d_in[1];
  const int*   widx = (const int*)d_in[2];
  const float* bias = (const float*)d_in[3];
  float* out = (float*)d_out;
  const int nnz = in_sizes[1];

  char* ws = (char*)d_ws;
  ushort* xp  = (ushort*)ws;                              // 55.1 MB
  float*  wd  = (float*)(ws + XP_BYTES);                  // 2.36 MB
  ushort* bm2 = (ushort*)(ws + XP_BYTES + WD_BYTES);      // 1.21 MB (pre-tiled B)

  hipMemsetAsync(wd, 0, WD_BYTES, stream);
  k_transpose<<<dim3(HP, NBATCH), 256, 0, stream>>>(x, xp);
  k_scatter<<<dim3((nnz + 255)/256), 256, 0, stream>>>(widx, wval, wd, nnz);
  k_convert2<<<dim3((NT*2*1024)/256), 256, 0, stream>>>(wd, bm2);
  k_gemm8<<<dim3(MTOT/256), 512, 0, stream>>>(xp, bm2, bias, out);
}

// Round 7
// 180.028 us; speedup vs baseline: 1.2722x; 1.0774x over previous
//
#include <hip/hip_runtime.h>

typedef unsigned short ushort;
typedef __attribute__((ext_vector_type(8))) short bf16x8;
typedef __attribute__((ext_vector_type(4))) float f32x4;
typedef __attribute__((ext_vector_type(4))) ushort us4;

#define NBATCH 32
#define ICN 256
#define OCN 256
#define HSZ 56
#define WSZ 56
#define HP 58
#define SPAT (HP*HP)            /* 3364 */
#define KTOT 2304               /* 9*256, k = (kh*3+kw)*256 + ic */
#define MTOT (NBATCH*HSZ*WSZ)   /* 100352 */
#define NT   (KTOT/64)          /* 36 K-tiles of BK=64 */

#define XP_BYTES ((size_t)NBATCH*SPAT*ICN*2)    /* 55,115,776 */
#define WD_BYTES ((size_t)OCN*KTOT*4)           /* 2,359,296  */
#define BM2_BYTES ((size_t)(NT+1)*2*1024*16)    /* 1.21 MB (+1 tile slack) */

__device__ __forceinline__ ushort f2bf(float f) {
  union { float f; unsigned u; } c; c.f = f;
  unsigned r = c.u + 0x7FFFu + ((c.u >> 16) & 1u);
  return (ushort)(r >> 16);
}

// x [N][IC][56][56] f32 -> xp [N][58][58][IC] bf16, halo rows/cols written as 0
__global__ void k_transpose(const float* __restrict__ x, ushort* __restrict__ xp) {
  __shared__ float tile[ICN*57];   // stride 57: conflict-free transpose read
  int h = blockIdx.x, n = blockIdx.y;          // h = padded row 0..57
  ushort* dst = xp + ((size_t)n*SPAT + (size_t)h*HP)*ICN;
  if (h == 0 || h == HP-1) {
    for (int e = threadIdx.x; e < HP*ICN/4; e += 256) ((us4*)dst)[e] = (us4){0,0,0,0};
    return;
  }
  const float* src = x + ((size_t)n*ICN*HSZ*WSZ) + (size_t)(h-1)*WSZ;
  for (int e = threadIdx.x; e < ICN*WSZ; e += 256) {
    int ic = e / WSZ, w = e - ic*WSZ;                 // w fastest -> coalesced read
    tile[ic*57 + w] = src[(size_t)ic*(HSZ*WSZ) + w];
  }
  __syncthreads();
  for (int e = threadIdx.x; e < ICN*HP; e += 256) {   // e = w*256+ic, w=0..57
    int w = e >> 8, ic = e & 255;
    dst[e] = (w == 0 || w == HP-1) ? (ushort)0 : f2bf(tile[ic*57 + (w-1)]);
  }
}

// COO scatter into dense fp32 W [oc][k], duplicates sum via atomicAdd
__global__ void k_scatter(const int* __restrict__ idx, const float* __restrict__ val,
                          float* __restrict__ wd, int nnz) {
  int i = blockIdx.x*256 + threadIdx.x;
  if (i >= nnz) return;
  int id = idx[i];
  int oc = id / (ICN*9);
  int rem = id - oc*(ICN*9);
  int ic = rem / 9;
  int k9 = rem - ic*9;                                // kh*3+kw
  atomicAdd(wd + (size_t)oc*KTOT + k9*ICN + ic, val[i]);
}

// Pre-tile B into LDS-slot order with quad swizzle baked in.
// Unit (t, kh) = [256 oc][4 phys quads]; slot s: r=s>>2, p=s&3,
// logical octet o = p ^ ((r>>1)&3).  bm2[e]*8 = 8 bf16 of wd[r][k(t,kh,o)..+8].
__global__ void k_convert2(const float* __restrict__ wd, ushort* __restrict__ bm2) {
  int e = blockIdx.x*256 + threadIdx.x;      // 0 .. NT*2*1024-1
  int t  = e >> 11;
  int kh = (e >> 10) & 1;
  int s  = e & 1023;
  int r  = s >> 2;
  int p  = s & 3;
  int o  = p ^ ((r >> 1) & 3);
  int t4 = t >> 2;
  int k  = t4*256 + ((t & 3) << 6) + (kh << 5) + o*8;
  const float* src = wd + (size_t)r*KTOT + k;
  float4 v0 = *(const float4*)(src);
  float4 v1 = *(const float4*)(src + 4);
  us4 lo, hi;
  lo[0]=f2bf(v0.x); lo[1]=f2bf(v0.y); lo[2]=f2bf(v0.z); lo[3]=f2bf(v0.w);
  hi[0]=f2bf(v1.x); hi[1]=f2bf(v1.y); hi[2]=f2bf(v1.z); hi[3]=f2bf(v1.w);
  ushort* dst = bm2 + (size_t)e*8;
  *(us4*)(dst) = lo; *(us4*)(dst+4) = hi;
}

// -------- 256x256 implicit-GEMM, 2 barriers/tile, pipelined fragments --------
// Within a tile, waves are NOT barrier-locked: fragment ds_reads are issued one
// phase ahead into ping-pong register sets with COUNTED lgkmcnt, so one wave's
// LDS reads overlap another wave's MFMA burst on the same SIMD.
// Barriers: mid-tile (WAR fence: ph2/3 stage B(t+2) into the in-use buffer c,
// whose kh-region reads completed before each wave's pre-barrier lgkm wait)
// and tile-end (after VMW4: all four units of tile t+1 landed; buffer swap).
// Per-tile stage issue order: Au0(t+1), Au1(t+1), Bk0(t+2), Bk1(t+2)
//  -> FIFO at tile end = [Bk*(t+1)(4), Au*(t+1)(4), Bk*(t+2)(4)]; VMW4 waits
//     exactly tile t+1's data.  Never vmcnt(0) in the main loop.

#define GLD(gsrc, ldst) __builtin_amdgcn_global_load_lds( \
    (const __attribute__((address_space(1))) void*)(gsrc), \
    (__attribute__((address_space(3))) void*)(ldst), 16, 0, 0)
#define BAR()  asm volatile("s_barrier" ::: "memory")
#define VMW4() asm volatile("s_waitcnt vmcnt(4)" ::: "memory")
#define LGKM0 do { asm volatile("s_waitcnt lgkmcnt(0)" ::: "memory"); \
                   __builtin_amdgcn_sched_barrier(0); } while (0)
#define LGKM4 do { asm volatile("s_waitcnt lgkmcnt(4)" ::: "memory"); \
                   __builtin_amdgcn_sched_barrier(0); } while (0)
#define LGKM8 do { asm volatile("s_waitcnt lgkmcnt(8)" ::: "memory"); \
                   __builtin_amdgcn_sched_barrier(0); } while (0)

#define STAGE_AU(T1, U) do { \
    const int t4_ = (T1) >> 2; const int khh_ = t4_/3, khw_ = t4_ - khh_*3; \
    const int koff_ = (khh_*HP + khw_)*256 + (((T1) & 3) << 6); \
    ushort* d_ = &Ab[(((T1)&1)*16384) + (U)*8192]; \
    GLD(xp + ((U) ? srcA10 : srcA00) + koff_, d_ + ldsOff0); \
    GLD(xp + ((U) ? srcA11 : srcA01) + koff_, d_ + ldsOff1); } while (0)

#define STAGE_BK(T1, KH) do { \
    const ushort* s_ = bm2 + ((size_t)((T1)*2 + (KH)))*8192; \
    ushort* d_ = &Bb[(((T1)&1)*16384) + (KH)*8192]; \
    GLD(s_ + srcB0, d_ + ldsOff0); \
    GLD(s_ + srcB1, d_ + ldsOff1); } while (0)

#define LOADA_TO(DST, KH, MH, C) do { \
    unsigned a_ = ((KH) ? aL1v : aL0v) + (unsigned)((C)*32768 + (MH)*8192); \
    asm volatile("ds_read_b128 %0, %4 offset:0\n\t" \
                 "ds_read_b128 %1, %4 offset:2048\n\t" \
                 "ds_read_b128 %2, %4 offset:4096\n\t" \
                 "ds_read_b128 %3, %4 offset:6144" \
                 : "=&v"(DST[0]), "=&v"(DST[1]), "=&v"(DST[2]), "=&v"(DST[3]) \
                 : "v"(a_)); } while (0)

#define LOADB_TO(DST, KH, C) do { \
    unsigned a_ = bLv + (unsigned)((C)*32768 + (KH)*16384); \
    asm volatile("ds_read_b128 %0, %4 offset:0\n\t" \
                 "ds_read_b128 %1, %4 offset:1024\n\t" \
                 "ds_read_b128 %2, %4 offset:2048\n\t" \
                 "ds_read_b128 %3, %4 offset:3072" \
                 : "=&v"(DST[0]), "=&v"(DST[1]), "=&v"(DST[2]), "=&v"(DST[3]) \
                 : "v"(a_)); } while (0)

#define MFMA16(MH, AV, BV) do { \
    __builtin_amdgcn_s_setprio(1); \
    _Pragma("unroll") \
    for (int f_ = 0; f_ < 4; ++f_) { \
      _Pragma("unroll") \
      for (int n_ = 0; n_ < 4; ++n_) \
        acc[(MH)*4+f_][n_] = __builtin_amdgcn_mfma_f32_16x16x32_bf16( \
            AV[f_], BV[n_], acc[(MH)*4+f_][n_], 0, 0, 0); \
    } \
    __builtin_amdgcn_s_setprio(0); } while (0)

__global__ __launch_bounds__(512, 2) void k_gemm8(const ushort* __restrict__ xp,
                                                  const ushort* __restrict__ bm2,
                                                  const float* __restrict__ bias,
                                                  float* __restrict__ out) {
  __shared__ __align__(128) ushort Ab[2*2*128*64];   // 64 KB
  __shared__ __align__(128) ushort Bb[2*2*256*32];   // 64 KB

  const int tid = threadIdx.x;
  const int lam = tid & 63;
  const int wv  = tid >> 6;            // 0..7
  const int wr  = wv >> 2;             // 0..1  (M half -> A unit)
  const int wc  = wv & 3;              // 0..3  (N quarter)
  const int la  = lam & 15;
  const int m0  = blockIdx.x * 256;

  const unsigned AbB = (unsigned)(uintptr_t)(__attribute__((address_space(3))) char*)Ab;
  const unsigned BbB = (unsigned)(uintptr_t)(__attribute__((address_space(3))) char*)Bb;

  // A read bases: byte addr = AbB + buf*32768 + u*16384 + mh*8192 + r*128 + p*16,
  // r = f*16+la, p = (kh*4 + oq) ^ (la&7), oq = lam>>4.
  const int q0 = (lam >> 4) ^ (la & 7);
  const unsigned aL0v = AbB + wr*16384 + la*128 + q0*16;
  const unsigned aL1v = AbB + wr*16384 + la*128 + (q0 ^ 4)*16;
  // B read base: byte addr = BbB + buf*32768 + kh*16384 + r*64 + p*16,
  // r = wc*64+f*16+la, p = (lam>>4) ^ ((la>>1)&3).
  const int pq = (lam >> 4) ^ ((la >> 1) & 3);
  const unsigned bLv = BbB + wc*4096 + la*64 + pq*16;

  // staging lane geometry (both A and B: per wave 2 instrs of 64 slots)
  const int ldsOff0 = (0*8 + wv)*512;          // ushort offsets, wave-uniform
  const int ldsOff1 = (1*8 + wv)*512;
  const int srcB0 = (0*8 + wv)*512 + lam*8;    // bm2 pre-tiled: contiguous
  const int srcB1 = (1*8 + wv)*512 + lam*8;
  // A: unit u, instr i: row r = (i*8+wv)*8 + (lam>>3); phys octet p = lam&7;
  // logical octet o = p ^ (r&7) = (lam&7) ^ (lam>>3).
  int srcA00, srcA01, srcA10, srcA11;
  {
    const int oA = (lam & 7) ^ (lam >> 3);
    int m, n, rem, oh, ow, r;
    r = (0*8 + wv)*8 + (lam >> 3);
    m = m0 + 0*128 + r; n = m/3136; rem = m - n*3136; oh = rem/56; ow = rem - oh*56;
    srcA00 = (n*SPAT + oh*HP + ow)*ICN + oA*8;
    r = (1*8 + wv)*8 + (lam >> 3);
    m = m0 + 0*128 + r; n = m/3136; rem = m - n*3136; oh = rem/56; ow = rem - oh*56;
    srcA01 = (n*SPAT + oh*HP + ow)*ICN + oA*8;
    r = (0*8 + wv)*8 + (lam >> 3);
    m = m0 + 1*128 + r; n = m/3136; rem = m - n*3136; oh = rem/56; ow = rem - oh*56;
    srcA10 = (n*SPAT + oh*HP + ow)*ICN + oA*8;
    r = (1*8 + wv)*8 + (lam >> 3);
    m = m0 + 1*128 + r; n = m/3136; rem = m - n*3136; oh = rem/56; ow = rem - oh*56;
    srcA11 = (n*SPAT + oh*HP + ow)*ICN + oA*8;
  }

  f32x4 acc[8][4];
#pragma unroll
  for (int a = 0; a < 8; ++a)
#pragma unroll
    for (int b = 0; b < 4; ++b) acc[a][b] = (f32x4){0.f, 0.f, 0.f, 0.f};

  bf16x8 av0_[4], av1_[4], bv0_[4], bv1_[4];   // static names only (rule #20)

  // prologue: tile-0 units + B of tile 1 (stays in flight across VMW4)
  STAGE_AU(0, 0); STAGE_AU(0, 1); STAGE_BK(0, 0); STAGE_BK(0, 1);
  STAGE_BK(1, 0); STAGE_BK(1, 1);
  VMW4();
  BAR();

  for (int t = 0; t < NT-1; ++t) {
    const int c = t & 1;
    // ph0: reads for ph0 + prefetch av(ph1); stage A-u0(t+1) -> buf c^1
    LOADB_TO(bv0_, 0, c); LOADA_TO(av0_, 0, 0, c);
    STAGE_AU(t+1, 0);
    LOADA_TO(av1_, 0, 1, c);
    LGKM4;                       // bv0,av0 done; av1 in flight under MFMA
    MFMA16(0, av0_, bv0_);
    // ph1: prefetch bv1(kh1) + av0(ph2); stage A-u1(t+1) -> buf c^1
    STAGE_AU(t+1, 1);
    LOADB_TO(bv1_, 1, c); LOADA_TO(av0_, 1, 0, c);
    LGKM8;                       // av1 done; bv1,av0' in flight
    MFMA16(1, av1_, bv0_);
    BAR();                       // mid-tile WAR fence (B-staging into buf c below)
    // ph2: prefetch av1(ph3); stage B-kh0(t+2) -> buf c (kh0 reads long done)
    STAGE_BK(t+2, 0);
    LOADA_TO(av1_, 1, 1, c);
    LGKM4;                       // bv1,av0' done; av1' in flight
    MFMA16(0, av0_, bv1_);
    // ph3: stage B-kh1(t+2) -> buf c
    STAGE_BK(t+2, 1);
    LGKM0;                       // av1' done
    MFMA16(1, av1_, bv1_);
    VMW4();                      // tile t+1 fully landed; Bk*(t+2) in flight
    BAR();
  }

  // peeled last tile (t = NT-1): no staging, no barriers needed
  {
    const int c = (NT-1) & 1;
    LOADB_TO(bv0_, 0, c); LOADA_TO(av0_, 0, 0, c);
    LOADA_TO(av1_, 0, 1, c);
    LGKM4;
    MFMA16(0, av0_, bv0_);
    LOADB_TO(bv1_, 1, c); LOADA_TO(av0_, 1, 0, c);
    LGKM8;
    MFMA16(1, av1_, bv0_);
    LOADA_TO(av1_, 1, 1, c);
    LGKM4;
    MFMA16(0, av0_, bv1_);
    LGKM0;
    MFMA16(1, av1_, bv1_);
  }

  // epilogue: lane l -> col(oc) = la, rows m = base + (l>>4)*4 + j
#pragma unroll
  for (int nn = 0; nn < 4; ++nn) {
    int oc = wc*64 + nn*16 + la;
    float bvs = bias[oc];
#pragma unroll
    for (int mf = 0; mf < 8; ++mf) {
      int m = m0 + wr*128 + mf*16 + ((lam >> 4) << 2);
      int n = m / 3136;
      int rem = m - n*3136;     // float4 never straddles n (3136 % 4 == 0)
      float4 o;
      o.x = acc[mf][nn][0] + bvs;
      o.y = acc[mf][nn][1] + bvs;
      o.z = acc[mf][nn][2] + bvs;
      o.w = acc[mf][nn][3] + bvs;
      *(float4*)(out + ((size_t)(n*OCN + oc))*3136 + rem) = o;
    }
  }
}

extern "C" void kernel_launch(void* const* d_in, const int* in_sizes, int n_in,
                              void* d_out, int out_size, void* d_ws, size_t ws_size,
                              hipStream_t stream) {
  const float* x    = (const float*)d_in[0];
  const float* wval = (const float*)d_in[1];
  const int*   widx = (const int*)d_in[2];
  const float* bias = (const float*)d_in[3];
  float* out = (float*)d_out;
  const int nnz = in_sizes[1];

  char* ws = (char*)d_ws;
  ushort* xp  = (ushort*)ws;                              // 55.1 MB
  float*  wd  = (float*)(ws + XP_BYTES);                  // 2.36 MB
  ushort* bm2 = (ushort*)(ws + XP_BYTES + WD_BYTES);      // 1.21 MB (pre-tiled B)

  hipMemsetAsync(wd, 0, WD_BYTES, stream);
  k_transpose<<<dim3(HP, NBATCH), 256, 0, stream>>>(x, xp);
  k_scatter<<<dim3((nnz + 255)/256), 256, 0, stream>>>(widx, wval, wd, nnz);
  k_convert2<<<dim3((NT*2*1024)/256), 256, 0, stream>>>(wd, bm2);
  k_gemm8<<<dim3(MTOT/256), 512, 0, stream>>>(xp, bm2, bias, out);
}

// Round 8
// 177.097 us; speedup vs baseline: 1.2933x; 1.0166x over previous
//
#include <hip/hip_runtime.h>

typedef unsigned short ushort;
typedef __attribute__((ext_vector_type(8))) short bf16x8;
typedef __attribute__((ext_vector_type(4))) float f32x4;
typedef __attribute__((ext_vector_type(4))) ushort us4;

#define NBATCH 32
#define ICN 256
#define OCN 256
#define HSZ 56
#define WSZ 56
#define HP 58
#define SPAT (HP*HP)            /* 3364 */
#define KTOT 2304               /* 9*256, k = (kh*3+kw)*256 + ic */
#define MTOT (NBATCH*HSZ*WSZ)   /* 100352 */
#define NT   (KTOT/64)          /* 36 K-tiles of BK=64 */

#define XP_BYTES ((size_t)NBATCH*SPAT*ICN*2)    /* 55,115,776 */
#define WD_BYTES ((size_t)OCN*KTOT*4)           /* 2,359,296  */

__device__ __forceinline__ ushort f2bf(float f) {
  union { float f; unsigned u; } c; c.f = f;
  unsigned r = c.u + 0x7FFFu + ((c.u >> 16) & 1u);
  return (ushort)(r >> 16);
}

// x [N][IC][56][56] f32 -> xp [N][58][58][IC] bf16, halo rows/cols written as 0
__global__ void k_transpose(const float* __restrict__ x, ushort* __restrict__ xp) {
  __shared__ float tile[ICN*57];   // stride 57: conflict-free transpose read
  int h = blockIdx.x, n = blockIdx.y;          // h = padded row 0..57
  ushort* dst = xp + ((size_t)n*SPAT + (size_t)h*HP)*ICN;
  if (h == 0 || h == HP-1) {
    for (int e = threadIdx.x; e < HP*ICN/4; e += 256) ((us4*)dst)[e] = (us4){0,0,0,0};
    return;
  }
  const float* src = x + ((size_t)n*ICN*HSZ*WSZ) + (size_t)(h-1)*WSZ;
  for (int e = threadIdx.x; e < ICN*WSZ; e += 256) {
    int ic = e / WSZ, w = e - ic*WSZ;                 // w fastest -> coalesced read
    tile[ic*57 + w] = src[(size_t)ic*(HSZ*WSZ) + w];
  }
  __syncthreads();
  for (int e = threadIdx.x; e < ICN*HP; e += 256) {   // e = w*256+ic, w=0..57
    int w = e >> 8, ic = e & 255;
    dst[e] = (w == 0 || w == HP-1) ? (ushort)0 : f2bf(tile[ic*57 + (w-1)]);
  }
}

// COO scatter into dense fp32 W [oc][k], duplicates sum via atomicAdd
__global__ void k_scatter(const int* __restrict__ idx, const float* __restrict__ val,
                          float* __restrict__ wd, int nnz) {
  int i = blockIdx.x*256 + threadIdx.x;
  if (i >= nnz) return;
  int id = idx[i];
  int oc = id / (ICN*9);
  int rem = id - oc*(ICN*9);
  int ic = rem / 9;
  int k9 = rem - ic*9;                                // kh*3+kw
  atomicAdd(wd + (size_t)oc*KTOT + k9*ICN + ic, val[i]);
}

// B in per-lane MFMA-fragment order for direct global->reg loads:
// 16B unit u = ((t*2+kh)*16 + wc*4 + f)*64 + lam holds
//   wd[oc = wc*64 + f*16 + (lam&15)][k = (t>>2)*256 + (t&3)*64 + kh*32 + (lam>>4)*8 .. +8]
// so each wave's load f is a contiguous 1KB run at (t,kh,wc) base.
__global__ void k_convert3(const float* __restrict__ wd, ushort* __restrict__ bm3) {
  int e = blockIdx.x*256 + threadIdx.x;      // 0 .. NT*2*16*64-1
  int lam = e & 63;
  int f   = (e >> 6) & 3;
  int wc  = (e >> 8) & 3;
  int kh  = (e >> 10) & 1;
  int t   = e >> 11;
  int oc  = wc*64 + f*16 + (lam & 15);
  int k   = (t >> 2)*256 + (t & 3)*64 + kh*32 + (lam >> 4)*8;
  const float* src = wd + (size_t)oc*KTOT + k;
  float4 v0 = *(const float4*)(src);
  float4 v1 = *(const float4*)(src + 4);
  us4 lo, hi;
  lo[0]=f2bf(v0.x); lo[1]=f2bf(v0.y); lo[2]=f2bf(v0.z); lo[3]=f2bf(v0.w);
  hi[0]=f2bf(v1.x); hi[1]=f2bf(v1.y); hi[2]=f2bf(v1.z); hi[3]=f2bf(v1.w);
  ushort* dst = bm3 + (size_t)e*8;
  *(us4*)(dst) = lo; *(us4*)(dst+4) = hi;
}

// ------ 256x256 implicit-GEMM: A via LDS (dbuf), B global->registers --------
// LDS traffic per tile drops 256KB -> 160KB (A reads 128KB + A stage 32KB);
// B fragments (8KB/wave/tile) come straight from L2-resident bm3 as 4x1KB
// coalesced global_load_dwordx4 per kh.  One barrier per tile (A-staging
// writes only the non-current buffer).  vmcnt FIFO per wave, steady state:
//   enter tile t: [bvA 4]
//   ph0: +bvB(t,kh1)4 +stageAu0(t+1)2 -> VMW6 drains bvA
//   ph1: +stageAu1(t+1)2
//   ph2: +bvA(t+1,kh0)4              -> VMW8 drains bvB
//   ph3: tile-end VMW4 drains both A stage units; BAR; swap.
// Never vmcnt(0) in the main loop.  All waits carry sched_barrier(0).

#define GLD(gsrc, ldst) __builtin_amdgcn_global_load_lds( \
    (const __attribute__((address_space(1))) void*)(gsrc), \
    (__attribute__((address_space(3))) void*)(ldst), 16, 0, 0)
#define BAR()  asm volatile("s_barrier" ::: "memory")
#define VMW(N) do { asm volatile("s_waitcnt vmcnt(" #N ")" ::: "memory"); \
                    __builtin_amdgcn_sched_barrier(0); } while (0)
#define LGKM(N) do { asm volatile("s_waitcnt lgkmcnt(" #N ")" ::: "memory"); \
                     __builtin_amdgcn_sched_barrier(0); } while (0)

#define STAGE_AU(T1, U) do { \
    const int t4_ = (T1) >> 2; const int khh_ = t4_/3, khw_ = t4_ - khh_*3; \
    const int koff_ = (khh_*HP + khw_)*256 + (((T1) & 3) << 6); \
    ushort* d_ = &Ab[(((T1)&1)*16384) + (U)*8192]; \
    GLD(xp + ((U) ? srcA10 : srcA00) + koff_, d_ + ldsOff0); \
    GLD(xp + ((U) ? srcA11 : srcA01) + koff_, d_ + ldsOff1); } while (0)

// B fragment loads: 4 x global_load_dwordx4, SGPR base + 32b voffset,
// imm offset f*1024.  Each instr reads a contiguous 1KB run (L2 hit).
#define GLB(DST, VOFF) \
    asm volatile("global_load_dwordx4 %0, %4, %5 offset:0\n\t" \
                 "global_load_dwordx4 %1, %4, %5 offset:1024\n\t" \
                 "global_load_dwordx4 %2, %4, %5 offset:2048\n\t" \
                 "global_load_dwordx4 %3, %4, %5 offset:3072" \
                 : "=&v"(DST[0]), "=&v"(DST[1]), "=&v"(DST[2]), "=&v"(DST[3]) \
                 : "v"(VOFF), "s"(bm3) : "memory")

#define LOADA_TO(DST, KH, MH, C) do { \
    unsigned a_ = ((KH) ? aL1v : aL0v) + (unsigned)((C)*32768 + (MH)*8192); \
    asm volatile("ds_read_b128 %0, %4 offset:0\n\t" \
                 "ds_read_b128 %1, %4 offset:2048\n\t" \
                 "ds_read_b128 %2, %4 offset:4096\n\t" \
                 "ds_read_b128 %3, %4 offset:6144" \
                 : "=&v"(DST[0]), "=&v"(DST[1]), "=&v"(DST[2]), "=&v"(DST[3]) \
                 : "v"(a_)); } while (0)

#define MFMA16(MH, AV, BV) do { \
    __builtin_amdgcn_s_setprio(1); \
    _Pragma("unroll") \
    for (int f_ = 0; f_ < 4; ++f_) { \
      _Pragma("unroll") \
      for (int n_ = 0; n_ < 4; ++n_) \
        acc[(MH)*4+f_][n_] = __builtin_amdgcn_mfma_f32_16x16x32_bf16( \
            AV[f_], BV[n_], acc[(MH)*4+f_][n_], 0, 0, 0); \
    } \
    __builtin_amdgcn_s_setprio(0); } while (0)

__global__ __launch_bounds__(512, 2) void k_gemm8(const ushort* __restrict__ xp,
                                                  const ushort* __restrict__ bm3,
                                                  const float* __restrict__ bias,
                                                  float* __restrict__ out) {
  __shared__ __align__(128) ushort Ab[2*2*128*64];   // 64 KB (A only)

  const int tid = threadIdx.x;
  const int lam = tid & 63;
  const int wv  = tid >> 6;            // 0..7
  const int wr  = wv >> 2;             // 0..1  (M half -> A unit)
  const int wc  = wv & 3;              // 0..3  (N quarter)
  const int la  = lam & 15;
  const int m0  = blockIdx.x * 256;

  const unsigned AbB = (unsigned)(uintptr_t)(__attribute__((address_space(3))) char*)Ab;

  // A read bases: byte addr = AbB + buf*32768 + u*16384 + mh*8192 + r*128 + p*16,
  // r = f*16+la, p = (kh*4 + oq) ^ (la&7), oq = lam>>4.
  const int q0 = (lam >> 4) ^ (la & 7);
  const unsigned aL0v = AbB + wr*16384 + la*128 + q0*16;
  const unsigned aL1v = AbB + wr*16384 + la*128 + (q0 ^ 4)*16;

  // B voffset base for this wave/lane (within bm3): + t*32768 + kh*16384
  const unsigned wcB = wc*4096 + lam*16;

  // A staging lane geometry (per wave 2 instrs of 64 slots)
  const int ldsOff0 = (0*8 + wv)*512;          // ushort offsets, wave-uniform
  const int ldsOff1 = (1*8 + wv)*512;
  // A: unit u, instr i: row r = (i*8+wv)*8 + (lam>>3); phys octet p = lam&7;
  // logical octet o = p ^ (r&7) = (lam&7) ^ (lam>>3).
  int srcA00, srcA01, srcA10, srcA11;
  {
    const int oA = (lam & 7) ^ (lam >> 3);
    int m, n, rem, oh, ow, r;
    r = (0*8 + wv)*8 + (lam >> 3);
    m = m0 + 0*128 + r; n = m/3136; rem = m - n*3136; oh = rem/56; ow = rem - oh*56;
    srcA00 = (n*SPAT + oh*HP + ow)*ICN + oA*8;
    r = (1*8 + wv)*8 + (lam >> 3);
    m = m0 + 0*128 + r; n = m/3136; rem = m - n*3136; oh = rem/56; ow = rem - oh*56;
    srcA01 = (n*SPAT + oh*HP + ow)*ICN + oA*8;
    r = (0*8 + wv)*8 + (lam >> 3);
    m = m0 + 1*128 + r; n = m/3136; rem = m - n*3136; oh = rem/56; ow = rem - oh*56;
    srcA10 = (n*SPAT + oh*HP + ow)*ICN + oA*8;
    r = (1*8 + wv)*8 + (lam >> 3);
    m = m0 + 1*128 + r; n = m/3136; rem = m - n*3136; oh = rem/56; ow = rem - oh*56;
    srcA11 = (n*SPAT + oh*HP + ow)*ICN + oA*8;
  }

  f32x4 acc[8][4];
#pragma unroll
  for (int a = 0; a < 8; ++a)
#pragma unroll
    for (int b = 0; b < 4; ++b) acc[a][b] = (f32x4){0.f, 0.f, 0.f, 0.f};

  bf16x8 av0_[4], av1_[4], bvA_[4], bvB_[4];   // static names only (rule #20)

  // prologue: stage A(0), load B(0,kh0); FIFO at wait: [stA0 2, stA1 2, bvA 4]
  STAGE_AU(0, 0); STAGE_AU(0, 1);
  GLB(bvA_, wcB);
  VMW(4);                      // A(0) landed; bvA in flight
  BAR();

  for (int t = 0; t < NT-1; ++t) {
    const int c = t & 1;
    const unsigned vb = (unsigned)t*32768 + wcB;
    // ph0: B(t,kh1) + stage A-u0(t+1); reads kh0 frags; VMW6 -> bvA ready
    GLB(bvB_, vb + 16384);
    STAGE_AU(t+1, 0);
    LOADA_TO(av0_, 0, 0, c); LOADA_TO(av1_, 0, 1, c);
    VMW(6);
    LGKM(4);                   // av0 ready; av1 in flight under MFMA
    MFMA16(0, av0_, bvA_);
    // ph1: stage A-u1(t+1); prefetch (kh1,mh0)
    STAGE_AU(t+1, 1);
    LOADA_TO(av0_, 1, 0, c);
    LGKM(4);                   // av1 ready; av0' in flight
    MFMA16(1, av1_, bvA_);
    // ph2: B(t+1,kh0); prefetch (kh1,mh1); VMW8 -> bvB ready
    GLB(bvA_, vb + 32768);
    LOADA_TO(av1_, 1, 1, c);
    VMW(8);
    LGKM(4);                   // av0' ready; av1' in flight
    MFMA16(0, av0_, bvB_);
    // ph3
    LGKM(0);                   // av1' ready
    MFMA16(1, av1_, bvB_);
    VMW(4);                    // A(t+1) units landed; bvA(t+1) in flight
    BAR();
  }

  // peeled last tile (t = NT-1): no staging
  {
    const int c = (NT-1) & 1;
    const unsigned vb = (unsigned)(NT-1)*32768 + wcB;
    GLB(bvB_, vb + 16384);
    LOADA_TO(av0_, 0, 0, c); LOADA_TO(av1_, 0, 1, c);
    VMW(4);                    // bvA ready (only bvB outstanding)
    LGKM(4);
    MFMA16(0, av0_, bvA_);
    LOADA_TO(av0_, 1, 0, c);
    LGKM(4);
    MFMA16(1, av1_, bvA_);
    LOADA_TO(av1_, 1, 1, c);
    VMW(0);                    // bvB ready
    LGKM(4);
    MFMA16(0, av0_, bvB_);
    LGKM(0);
    MFMA16(1, av1_, bvB_);
  }

  // epilogue: lane l -> col(oc) = la, rows m = base + (l>>4)*4 + j
#pragma unroll
  for (int nn = 0; nn < 4; ++nn) {
    int oc = wc*64 + nn*16 + la;
    float bvs = bias[oc];
#pragma unroll
    for (int mf = 0; mf < 8; ++mf) {
      int m = m0 + wr*128 + mf*16 + ((lam >> 4) << 2);
      int n = m / 3136;
      int rem = m - n*3136;     // float4 never straddles n (3136 % 4 == 0)
      float4 o;
      o.x = acc[mf][nn][0] + bvs;
      o.y = acc[mf][nn][1] + bvs;
      o.z = acc[mf][nn][2] + bvs;
      o.w = acc[mf][nn][3] + bvs;
      *(float4*)(out + ((size_t)(n*OCN + oc))*3136 + rem) = o;
    }
  }
}

extern "C" void kernel_launch(void* const* d_in, const int* in_sizes, int n_in,
                              void* d_out, int out_size, void* d_ws, size_t ws_size,
                              hipStream_t stream) {
  const float* x    = (const float*)d_in[0];
  const float* wval = (const float*)d_in[1];
  const int*   widx = (const int*)d_in[2];
  const float* bias = (const float*)d_in[3];
  float* out = (float*)d_out;
  const int nnz = in_sizes[1];

  char* ws = (char*)d_ws;
  ushort* xp  = (ushort*)ws;                              // 55.1 MB
  float*  wd  = (float*)(ws + XP_BYTES);                  // 2.36 MB
  ushort* bm3 = (ushort*)(ws + XP_BYTES + WD_BYTES);      // 1.125 MB (frag-order B)

  hipMemsetAsync(wd, 0, WD_BYTES, stream);
  k_transpose<<<dim3(HP, NBATCH), 256, 0, stream>>>(x, xp);
  k_scatter<<<dim3((nnz + 255)/256), 256, 0, stream>>>(widx, wval, wd, nnz);
  k_convert3<<<dim3((NT*2*16*64)/256), 256, 0, stream>>>(wd, bm3);
  k_gemm8<<<dim3(MTOT/256), 512, 0, stream>>>(xp, bm3, bias, out);
}